// Round 5
// baseline (95.572 us; speedup 1.0000x reference)
//
#include <hip/hip_runtime.h>
#include <hip/hip_bf16.h>

#define NFEAT 256
#define NATOMS 4096
#define NCLAUSES 512
#define ROWS 8
#define XPAD 12          // floats per feature column: uniform LDS bank spread (gcd(12,32)=4 -> 8 groups x 4 banks)
#define BLOCK 512        // 8 waves: 1 clause per thread, max TLP (8 waves/SIMD at 1024 blocks)

// hardware transcendentals: v_exp_f32 computes 2^x
#define EXP2F(v) __builtin_amdgcn_exp2f(v)
#define RCPF(v)  __builtin_amdgcn_rcpf(v)

// Precompute:
//  - per-atom packed params abf[a] = {A, B, float_as_int(fid*XPAD), unused}
//    where e = exp(-z) = exp2(A*x + B);  A = -s*B_CONST*log2e*w ; B = s*B_CONST*log2e*(eta - eps)
//  - CSR clause offsets seg[0..512] via binary search over sorted clause_ids
//  - gl[c] = gate[c]*leaf[c]
__global__ void cln_pre(const float* __restrict__ w, const float* __restrict__ eta,
                        const float* __restrict__ leaf, const float* __restrict__ gate,
                        const int* __restrict__ fid, const int* __restrict__ sgn,
                        const int* __restrict__ cid,
                        float4* __restrict__ abf, int* __restrict__ seg,
                        float* __restrict__ gl) {
    int i = blockIdx.x * blockDim.x + threadIdx.x;
    const float K = 144.269504088896340736f;  // B_CONST * log2(e), B=100
    if (i < NATOMS) {
        float s = (sgn[i] == 0) ? -1.f : 1.f;
        float a2 = -s * K * w[i];
        float b2 =  s * K * (eta[i] - 0.01f);
        abf[i] = make_float4(a2, b2, __int_as_float(fid[i] * XPAD), 0.f);
    }
    if (i <= NCLAUSES) {
        // lower_bound: first index with cid[idx] >= i
        int lo = 0, hi = NATOMS;
        while (lo < hi) {
            int mid = (lo + hi) >> 1;
            if (cid[mid] < i) lo = mid + 1; else hi = mid;
        }
        seg[i] = lo;
    }
    if (i < NCLAUSES) gl[i] = gate[i] * leaf[i];
}

__global__ __launch_bounds__(BLOCK, 4) void cln_main(
        const float* __restrict__ x, const float4* __restrict__ abf,
        const int* __restrict__ seg, const float* __restrict__ gl,
        float* __restrict__ y) {
    __shared__ __align__(16) float xT[NFEAT * XPAD];   // 12 KB, transposed x tile; reused for reduce

    const int tid = threadIdx.x;
    const int row0 = blockIdx.x * ROWS;

    // Stage 8 rows of x, transposed: xT[fid*XPAD + r]. 512 threads x 4 elems.
#pragma unroll
    for (int k = 0; k < (ROWS * NFEAT) / BLOCK; ++k) {
        const int idx = k * BLOCK + tid;
        const int row = idx >> 8;          // /NFEAT
        const int col = idx & (NFEAT - 1);
        xT[col * XPAD + row] = x[(row0 + row) * NFEAT + col];
    }
    __syncthreads();

    // One whole clause per thread (c = tid): product t-norm accumulated
    // directly. No logs, no atomics, no divergence on clause boundaries.
    // p>=1 always. Clamp at 1e37: p=inf then ev=0 gives fmaf(inf,0,inf)=NaN.
    // Clamped clause -> rcp ~ 1e-37 ~ 0, matching the reference's underflow.
    const int c = tid;
    const int s = seg[c];
    const int e = seg[c + 1];
    float p[ROWS];
#pragma unroll
    for (int r = 0; r < ROWS; ++r) p[r] = 1.f;

    // Software-pipelined abf prefetch: issue load for a+1 before computing a.
    float4 t = abf[s];           // empty clause: loads junk, never used (loop skipped)
    for (int a = s; a < e; ++a) {
        const int an = (a + 1 < e) ? (a + 1) : a;
        const float4 tn = abf[an];
        const int xo = __float_as_int(t.z);
        const float4 xa = *(const float4*)(xT + xo);
        const float4 xb = *(const float4*)(xT + xo + 4);
        const float xv[ROWS] = {xa.x, xa.y, xa.z, xa.w, xb.x, xb.y, xb.z, xb.w};
#pragma unroll
        for (int r = 0; r < ROWS; ++r) {
            float ev = EXP2F(fmaf(t.x, xv[r], t.y));
            p[r] = fminf(fmaf(p[r], ev, p[r]), 1e37f);   // p *= (1 + e), clamped
        }
        t = tn;
    }

    const float g = gl[c];
    float acc[ROWS];
#pragma unroll
    for (int r = 0; r < ROWS; ++r)
        acc[r] = g * RCPF(p[r]);     // empty clause: rcp(1)=1 -> +g, matches exp(0)=1

    // Block reduction: wave shuffle-reduce each row, 8 wave-partials via LDS.
    __syncthreads();                 // xT no longer needed as x-tile
    float* red = xT;                 // 8 waves * 8 rows
    const int wave = tid >> 6;
    const int lane = tid & 63;
#pragma unroll
    for (int r = 0; r < ROWS; ++r) {
        float v = acc[r];
#pragma unroll
        for (int off = 32; off > 0; off >>= 1)
            v += __shfl_down(v, off, 64);
        if (lane == 0) red[wave * ROWS + r] = v;
    }
    __syncthreads();
    if (tid < ROWS) {
        float sres = 0.f;
#pragma unroll
        for (int wv = 0; wv < BLOCK / 64; ++wv)
            sres += red[wv * ROWS + tid];
        y[row0 + tid] = sres;
    }
}

extern "C" void kernel_launch(void* const* d_in, const int* in_sizes, int n_in,
                              void* d_out, int out_size, void* d_ws, size_t ws_size,
                              hipStream_t stream) {
    const float* x    = (const float*)d_in[0];
    const float* w    = (const float*)d_in[1];
    const float* eta  = (const float*)d_in[2];
    const float* leaf = (const float*)d_in[3];
    const float* gate = (const float*)d_in[4];
    const int*   fid  = (const int*)d_in[5];
    const int*   sgn  = (const int*)d_in[6];
    const int*   cid  = (const int*)d_in[7];
    float* y = (float*)d_out;

    char* ws = (char*)d_ws;
    float4* abf = (float4*)ws;                                   // 64 KB
    int*    seg = (int*)(ws + NATOMS * sizeof(float4));          // 2052 B
    float*  gl  = (float*)(ws + NATOMS * sizeof(float4) + (NCLAUSES + 1 + 3) * sizeof(int)); // 2 KB

    const int bsz = in_sizes[0] / NFEAT;  // 8192

    cln_pre<<<NATOMS / 256, 256, 0, stream>>>(w, eta, leaf, gate, fid, sgn, cid,
                                              abf, seg, gl);
    cln_main<<<bsz / ROWS, BLOCK, 0, stream>>>(x, abf, seg, gl, y);
}